// Round 1
// baseline (210.376 us; speedup 1.0000x reference)
//
#include <hip/hip_runtime.h>
#include <hip/hip_bf16.h>

typedef __hip_bfloat16 BF16;
typedef __attribute__((ext_vector_type(8))) short bf16x8;
typedef __attribute__((ext_vector_type(4))) float f32x4;
typedef __attribute__((ext_vector_type(4))) int int4v;

#define MTOK 12608      // 64*197 tokens
#define D_IN 768
#define KAUG 832        // 768 + 64 (E*R)
#define N_QKV 2304

// ---------------- prep kernels ----------------
__global__ __launch_bounds__(256) void prep_waug_k(const float* __restrict__ qkv_w,
                                                   const float* __restrict__ lora_b,
                                                   BF16* __restrict__ Waug) {
  int idx = blockIdx.x*256 + threadIdx.x;
  if (idx >= N_QKV*KAUG) return;
  int k = idx / KAUG, c = idx - k*KAUG;
  float v = (c < D_IN) ? qkv_w[k*D_IN + c] : lora_b[(size_t)(c - D_IN)*N_QKV + k];
  Waug[idx] = (BF16)v;
}

__global__ __launch_bounds__(256) void prep_pb_k(const float* __restrict__ proj_w,
                                                 BF16* __restrict__ Pb) {
  int idx = blockIdx.x*256 + threadIdx.x;
  if (idx < D_IN*D_IN) Pb[idx] = (BF16)proj_w[idx];
}

__global__ __launch_bounds__(256) void prep_lat_k(const float* __restrict__ lora_a,
                                                  BF16* __restrict__ LAt) {
  int idx = blockIdx.x*256 + threadIdx.x;
  if (idx >= 64*D_IN) return;
  int j = idx / D_IN, d = idx - j*D_IN;
  // LAt[j][d] = lora_a[e=j>>3][d][r=j&7]
  LAt[idx] = (BF16)lora_a[(size_t)(j >> 3)*6144 + d*8 + (j & 7)];
}

// ---------------- token prep: bf16 cast + gate softmax ----------------
__global__ __launch_bounds__(256) void token_prep_k(const float* __restrict__ tokens,
                                                    const float* __restrict__ gate_w,
                                                    BF16* __restrict__ Aaug,
                                                    float* __restrict__ gates) {
  int w = blockIdx.x*4 + (threadIdx.x >> 6);
  int lane = threadIdx.x & 63;
  if (w >= MTOK) return;
  const float* x = tokens + (size_t)w*D_IN;
  float xv[12];
  #pragma unroll
  for (int i=0;i<12;++i) xv[i] = x[lane + 64*i];
  #pragma unroll
  for (int i=0;i<12;++i) Aaug[(size_t)w*KAUG + lane + 64*i] = (BF16)xv[i];
  float g[8] = {0,0,0,0,0,0,0,0};
  #pragma unroll
  for (int i=0;i<12;++i) {
    int d = lane + 64*i;
    #pragma unroll
    for (int e=0;e<8;++e) g[e] += xv[i]*gate_w[e*D_IN + d];
  }
  #pragma unroll
  for (int e=0;e<8;++e) {
    #pragma unroll
    for (int off=32; off; off >>= 1) g[e] += __shfl_xor(g[e], off);
  }
  float mx = g[0];
  #pragma unroll
  for (int e=1;e<8;++e) mx = fmaxf(mx, g[e]);
  float pe[8]; float ssum = 0.f;
  #pragma unroll
  for (int e=0;e<8;++e) { pe[e] = __expf(g[e]-mx); ssum += pe[e]; }
  float inv = 1.f/ssum;
  if (lane < 8) {
    float val = 0.f;
    #pragma unroll
    for (int e=0;e<8;++e) val = (lane==e) ? pe[e]*inv : val;  // static idx (no scratch)
    gates[(size_t)w*8 + lane] = val;
  }
}

// ---------------- GEMM-BT template ----------------
// C[M,N] = A[M,K](row-major, lda) * Bt[N,K](row-major, ldb)^T, bf16 in, fp32 acc.
template<int ROWS>
__device__ __forceinline__ void stage_bt(const BF16* __restrict__ g, int ldg, int row0, int M,
                                         BF16* lds, int kbase, int t) {
  constexpr int NIT = ROWS*8/256;     // 16B chunks per thread (BK=64 -> 8 chunks/row)
  #pragma unroll
  for (int it=0; it<NIT; ++it) {
    int c = it*256 + t;
    int r = c >> 3, kc = c & 7;
    int rg = row0 + r;
    rg = (rg < M) ? rg : (M-1);
    const BF16* gp = g + (size_t)rg*ldg + kbase + kc*8;
    BF16* lp = lds + (it*256 + (t & ~63))*8;   // wave-uniform base; HW adds lane*16
    __builtin_amdgcn_global_load_lds((const __attribute__((address_space(1))) void*)gp,
                                     (__attribute__((address_space(3))) void*)lp, 16, 0, 0);
  }
}

// EPI: 0 = *gates -> bf16 (h-GEMM, N=64), 1 = +bias -> bf16, 2 = +bias -> fp32
template<int BM, int BN, int EPI>
__global__ __launch_bounds__(256,3) void gemm_bt_k(const BF16* __restrict__ A, int lda,
                                                   const BF16* __restrict__ Bt, int ldb,
                                                   const float* __restrict__ aux,
                                                   void* __restrict__ Cv, int ldc,
                                                   int M, int K) {
  constexpr int BK = 64;
  constexpr int WM = BM/2, WN = BN/2;
  constexpr int MF = WM/16, NF = WN/16;
  __shared__ BF16 Al[BM*BK];
  __shared__ BF16 Bl[BN*BK];
  const int n0 = blockIdx.x*BN, m0 = blockIdx.y*BM;
  const int t = threadIdx.x, lane = t & 63, wid = t >> 6;
  const int wm = (wid >> 1)*WM, wn = (wid & 1)*WN;
  f32x4 acc[MF][NF] = {};
  const int KT = K/BK;
  for (int kt=0; kt<KT; ++kt) {
    stage_bt<BM>(A, lda, m0, M, Al, kt*BK, t);
    stage_bt<BN>(Bt, ldb, n0, 1<<30, Bl, kt*BK, t);
    __syncthreads();
    #pragma unroll
    for (int kk=0; kk<2; ++kk) {
      bf16x8 a[MF], b[NF];
      const int col = kk*32 + (lane >> 4)*8;
      #pragma unroll
      for (int m=0;m<MF;++m) a[m] = *(const bf16x8*)(Al + (wm + m*16 + (lane & 15))*BK + col);
      #pragma unroll
      for (int n=0;n<NF;++n) b[n] = *(const bf16x8*)(Bl + (wn + n*16 + (lane & 15))*BK + col);
      #pragma unroll
      for (int m=0;m<MF;++m)
        #pragma unroll
        for (int n=0;n<NF;++n)
          acc[m][n] = __builtin_amdgcn_mfma_f32_16x16x32_bf16(a[m], b[n], acc[m][n], 0, 0, 0);
    }
    __syncthreads();
  }
  // epilogue; C/D layout: col = lane&15, row = (lane>>4)*4 + j  [m89/m91]
  #pragma unroll
  for (int m=0;m<MF;++m) {
    #pragma unroll
    for (int n=0;n<NF;++n) {
      const int rb = m0 + wm + m*16 + (lane >> 4)*4;
      const int c = n0 + wn + n*16 + (lane & 15);
      #pragma unroll
      for (int j=0;j<4;++j) {
        const int r = rb + j;
        if (r < M) {
          float v = acc[m][n][j];
          if (EPI == 0) {
            v *= aux[(size_t)r*8 + (c >> 3)];
            ((BF16*)Cv)[(size_t)r*ldc + c] = (BF16)v;
          } else if (EPI == 1) {
            v += aux[c];
            ((BF16*)Cv)[(size_t)r*ldc + c] = (BF16)v;
          } else {
            v += aux[c];
            ((float*)Cv)[(size_t)r*ldc + c] = v;
          }
        }
      }
    }
  }
}

// ---------------- attention: one block per (b,h) ----------------
__global__ __launch_bounds__(256,2) void attn_k(const BF16* __restrict__ QKV,
                                                BF16* __restrict__ O) {
  constexpr int KSTR = 72;   // 144B rows: bank-start stride 4 -> 2-way (free), 16B aligned
  constexpr int VSTR = 232;  // 464B rows: bank-start stride 20 -> 2-way, 16B aligned
  constexpr int PSTR = 40;   // 80B rows
  __shared__ BF16 Kl[208*KSTR];
  __shared__ BF16 Vt[64*VSTR];
  __shared__ BF16 Pl[4][16*PSTR];
  const int bh = blockIdx.x;
  const int b = bh / 12, h = bh - b*12;
  const size_t rowbase = (size_t)b*197;
  const int t = threadIdx.x, lane = t & 63, wid = t >> 6;
  const BF16 z = (BF16)0.0f;
  // stage K rows 0..207 (pad rows zeroed)
  for (int c = t; c < 208*8; c += 256) {
    int r = c >> 3, kc = c & 7;
    int4v val = {0,0,0,0};
    if (r < 197) val = *(const int4v*)(QKV + (rowbase + r)*N_QKV + 768 + h*64 + kc*8);
    *(int4v*)(Kl + r*KSTR + kc*8) = val;
  }
  // stage V transposed: Vt[d][k]
  for (int c = t; c < 208*8; c += 256) {
    int r = c >> 3, kc = c & 7;
    if (r < 197) {
      int4v val = *(const int4v*)(QKV + (rowbase + r)*N_QKV + 1536 + h*64 + kc*8);
      const BF16* pv = (const BF16*)&val;
      #pragma unroll
      for (int i=0;i<8;++i) Vt[(kc*8 + i)*VSTR + r] = pv[i];
    } else {
      #pragma unroll
      for (int i=0;i<8;++i) Vt[(kc*8 + i)*VSTR + r] = z;
    }
  }
  for (int c = t; c < 64*24; c += 256) {       // zero k = 208..231
    int d = c / 24, k2 = 208 + (c - d*24);
    Vt[d*VSTR + k2] = z;
  }
  __syncthreads();

  for (int chunk = wid; chunk < 13; chunk += 4) {
    const int q0 = chunk*16;
    int qr = q0 + (lane & 15);
    qr = (qr < 197) ? qr : 196;                // clamp pad rows; stores masked later
    bf16x8 qa[2];
    #pragma unroll
    for (int kk=0;kk<2;++kk)
      qa[kk] = *(const bf16x8*)(QKV + (rowbase + qr)*N_QKV + h*64 + kk*32 + (lane >> 4)*8);
    f32x4 zf = {0.f,0.f,0.f,0.f};
    f32x4 s[14];
    #pragma unroll
    for (int nf=0;nf<14;++nf) s[nf] = zf;      // s[13] stays zero (PV pad chunk)
    #pragma unroll
    for (int nf=0;nf<13;++nf) {
      #pragma unroll
      for (int kk=0;kk<2;++kk) {
        bf16x8 kb = *(const bf16x8*)(Kl + (nf*16 + (lane & 15))*KSTR + kk*32 + (lane >> 4)*8);
        s[nf] = __builtin_amdgcn_mfma_f32_16x16x32_bf16(qa[kk], kb, s[nf], 0, 0, 0);
      }
    }
    // row softmax in C-layout: lane owns rows (lane>>4)*4+j, cols nf*16+(lane&15)
    float mrow[4] = {-1e30f,-1e30f,-1e30f,-1e30f};
    float lrow[4] = {0.f,0.f,0.f,0.f};
    #pragma unroll
    for (int nf=0;nf<13;++nf) {
      const int cg = nf*16 + (lane & 15);
      #pragma unroll
      for (int j=0;j<4;++j) {
        float v = s[nf][j]*0.125f;
        v = (cg < 197) ? v : -1e30f;
        s[nf][j] = v;
        mrow[j] = fmaxf(mrow[j], v);
      }
    }
    #pragma unroll
    for (int j=0;j<4;++j) {
      #pragma unroll
      for (int off=1; off<16; off<<=1) mrow[j] = fmaxf(mrow[j], __shfl_xor(mrow[j], off));
    }
    #pragma unroll
    for (int nf=0;nf<13;++nf) {
      #pragma unroll
      for (int j=0;j<4;++j) {
        float p = __expf(s[nf][j] - mrow[j]);
        s[nf][j] = p;
        lrow[j] += p;
      }
    }
    #pragma unroll
    for (int j=0;j<4;++j) {
      #pragma unroll
      for (int off=1; off<16; off<<=1) lrow[j] += __shfl_xor(lrow[j], off);
    }
    // PV: repack P through wave-private LDS, MFMA against Vt
    BF16* P = &Pl[wid][0];
    f32x4 o[4] = {};
    #pragma unroll
    for (int kc=0; kc<7; ++kc) {
      asm volatile("s_waitcnt lgkmcnt(0)" ::: "memory");   // prev pa read done before overwrite
      __builtin_amdgcn_sched_barrier(0);
      #pragma unroll
      for (int half=0; half<2; ++half) {
        const int nf = kc*2 + half;
        #pragma unroll
        for (int j=0;j<4;++j)
          P[((lane >> 4)*4 + j)*PSTR + half*16 + (lane & 15)] = (BF16)s[nf][j];
      }
      asm volatile("s_waitcnt lgkmcnt(0)" ::: "memory");   // writes visible before read
      __builtin_amdgcn_sched_barrier(0);
      bf16x8 pa = *(const bf16x8*)(P + (lane & 15)*PSTR + (lane >> 4)*8);
      #pragma unroll
      for (int df=0; df<4; ++df) {
        bf16x8 vb = *(const bf16x8*)(Vt + (df*16 + (lane & 15))*VSTR + kc*32 + (lane >> 4)*8);
        o[df] = __builtin_amdgcn_mfma_f32_16x16x32_bf16(pa, vb, o[df], 0, 0, 0);
      }
    }
    #pragma unroll
    for (int df=0; df<4; ++df) {
      #pragma unroll
      for (int j=0;j<4;++j) {
        const int r = q0 + (lane >> 4)*4 + j;
        if (r < 197) {
          float val = o[df][j] / lrow[j];
          O[(rowbase + r)*768 + h*64 + df*16 + (lane & 15)] = (BF16)val;
        }
      }
    }
  }
}

// ---------------- host launcher ----------------
extern "C" void kernel_launch(void* const* d_in, const int* in_sizes, int n_in,
                              void* d_out, int out_size, void* d_ws, size_t ws_size,
                              hipStream_t stream) {
  const float* tokens = (const float*)d_in[0];
  const float* qkv_w  = (const float*)d_in[1];
  const float* qkv_b  = (const float*)d_in[2];
  const float* proj_w = (const float*)d_in[3];
  const float* proj_b = (const float*)d_in[4];
  const float* gate_w = (const float*)d_in[5];
  const float* lora_a = (const float*)d_in[6];
  const float* lora_b = (const float*)d_in[7];

  size_t off = 0;
  auto take = [&](size_t bytes) {
    off = (off + 255) & ~(size_t)255;
    void* p = (char*)d_ws + off;
    off += bytes;
    return p;
  };
  BF16* Waug  = (BF16*)take((size_t)N_QKV*KAUG*2);   // [2304][832]
  BF16* Pb    = (BF16*)take((size_t)D_IN*D_IN*2);    // [768][768]
  BF16* LAt   = (BF16*)take((size_t)64*D_IN*2);      // [64][768]
  BF16* Aaug  = (BF16*)take((size_t)MTOK*KAUG*2);    // [12608][832]
  float* gates= (float*)take((size_t)MTOK*8*4);      // [12608][8]
  BF16* QKVb  = (BF16*)take((size_t)MTOK*N_QKV*2);   // [12608][2304]
  BF16* Oc    = (BF16*)take((size_t)MTOK*D_IN*2);    // [12608][768]

  prep_waug_k<<<(N_QKV*KAUG + 255)/256, 256, 0, stream>>>(qkv_w, lora_b, Waug);
  prep_pb_k<<<(D_IN*D_IN + 255)/256, 256, 0, stream>>>(proj_w, Pb);
  prep_lat_k<<<(64*D_IN + 255)/256, 256, 0, stream>>>(lora_a, LAt);
  token_prep_k<<<MTOK/4, 256, 0, stream>>>(tokens, gate_w, Aaug, gates);
  // h-GEMM: hg[t][j] = (tokens . lora_a[:,:,r])_e * gate  -> Aaug cols 768..831
  gemm_bt_k<64,64,0><<<dim3(1, MTOK/64), 256, 0, stream>>>(
      Aaug, KAUG, LAt, D_IN, gates, (void*)(Aaug + 768), KAUG, MTOK, D_IN);
  // augmented QKV GEMM: [tokens|hg] @ [qkv_w ; lora_b]^T + qkv_b
  gemm_bt_k<128,128,1><<<dim3(N_QKV/128, (MTOK + 127)/128), 256, 0, stream>>>(
      Aaug, KAUG, Waug, KAUG, qkv_b, (void*)QKVb, N_QKV, MTOK, KAUG);
  attn_k<<<768, 256, 0, stream>>>(QKVb, Oc);
  gemm_bt_k<128,128,2><<<dim3(D_IN/128, (MTOK + 127)/128), 256, 0, stream>>>(
      Oc, D_IN, Pb, D_IN, proj_b, d_out, D_IN, MTOK, D_IN);
}